// Round 9
// baseline (543.927 us; speedup 1.0000x reference)
//
#include <hip/hip_runtime.h>
#include <cstdint>
#include <cstddef>

#define T_ 4
#define N_ 512
#define C_ 256
#define V_ 25
#define H_ 8

typedef _Float16 half8_t __attribute__((ext_vector_type(8)));
typedef float f32x16 __attribute__((ext_vector_type(16)));

__device__ __forceinline__ f32x16 mfma16(half8_t a, half8_t b, f32x16 c) {
  return __builtin_amdgcn_mfma_f32_32x32x16_f16(a, b, c, 0, 0, 0);
}

// ---- KW: pre-swizzled, BN-scaled, fp16-split weights (verbatim r7) ----
// Wstg: i = ((((c*4+p)*4+s)*2+m)*4+rt)*512 + lane*8 + j
//   chunks 0..5 = qkv (br=c>>1, rows (c&1)*128+..), 6..7 = proj
__global__ void kw_stage(const float* __restrict__ wq, const float* __restrict__ wk,
                         const float* __restrict__ wv, const float* __restrict__ wp,
                         const float* __restrict__ qg, const float* __restrict__ qvar,
                         const float* __restrict__ kg, const float* __restrict__ kvar,
                         const float* __restrict__ vg, const float* __restrict__ vvar,
                         const float* __restrict__ pg, const float* __restrict__ pvar,
                         _Float16* __restrict__ Wstg) {
  int i = blockIdx.x * 512 + threadIdx.x;          // < 524288
  int j = i & 7, lane = (i >> 3) & 63, rt = (i >> 9) & 3, m = (i >> 11) & 1;
  int s = (i >> 12) & 3, p = (i >> 14) & 3, c = i >> 16;
  int kt = p * 4 + s;
  int row = rt * 32 + (lane & 31);
  int k = kt * 16 + (lane >> 5) * 8 + j;
  const float *w, *g, *va;
  int grow;
  if (c < 6) {
    int br = c >> 1;
    w = br == 0 ? wq : br == 1 ? wk : wv;
    g = br == 0 ? qg : br == 1 ? kg : vg;
    va = br == 0 ? qvar : br == 1 ? kvar : vvar;
    grow = (c & 1) * 128 + row;
  } else {
    w = wp; g = pg; va = pvar;
    grow = (c - 6) * 128 + row;
  }
  float sc = g[grow] / sqrtf(va[grow] + 1e-5f);
  float wv_ = w[grow * 256 + k] * sc;
  _Float16 hi = (_Float16)wv_;
  Wstg[i] = (m == 0) ? hi : (_Float16)(wv_ - (float)hi);
}

// ---- KX: fp16 hi/lo x-panels, kt-major coalesced (verbatim r7) ----
// X16 idx(n,m,kt,col,e) = (((n*2+m)*16 + kt)*100 + col)*16 + e ; col = t*25+v
__global__ void kx_stage(const float* __restrict__ x, _Float16* __restrict__ X16) {
  __shared__ float Xt[256 * 28];
  const int n = blockIdx.x, tid = threadIdx.x;   // 256 threads
  for (int t = 0; t < 4; ++t) {
    __syncthreads();
    for (int i = tid; i < 6400; i += 256) {
      int k = i / 25, v = i - k * 25;
      Xt[k * 28 + v] = x[(size_t)(t * N_ + n) * 6400 + i];
    }
    __syncthreads();
    for (int jj = tid; jj < 800; jj += 256) {
      int kt = jj / 50, r = jj - kt * 50;
      int v = r >> 1, lkg = r & 1;
      int k0 = kt * 16 + lkg * 8;
      half8_t hi, lo;
#pragma unroll
      for (int e = 0; e < 8; ++e) {
        float f = Xt[(k0 + e) * 28 + v];
        _Float16 h = (_Float16)f;
        hi[e] = h;
        lo[e] = (_Float16)(f - (float)h);
      }
      int col = t * 25 + v;
      size_t bhi = ((((size_t)n * 2 + 0) * 16 + kt) * 100 + col) * 16 + lkg * 8;
      size_t blo = ((((size_t)n * 2 + 1) * 16 + kt) * 100 + col) * 16 + lkg * 8;
      *(half8_t*)(X16 + bhi) = hi;
      *(half8_t*)(X16 + blo) = lo;
    }
  }
}

// Ms swizzled byte offset (verbatim — bit-exact r4-r8); rows < 64 here
#define MS_BYTE(colx, rowx) ((colx) * 256 + (((rowx) * 4) ^ (((colx) & 7) << 4)))

// Stage 8KB phase (2 kt x 2 m x 2 rtl x 1KB) of chunk cc, row-half rh, into Abuf[bs]
#define STAGE_HALF(cc, kt0, bs)                                                     \
  do {                                                                              \
    int sb_ = tid >> 6;                                                             \
    _Pragma("unroll")                                                               \
    for (int q_ = 0; q_ < 2; ++q_) {                                                \
      int kt_ = (kt0) + q_;                                                         \
      const _Float16* sp_ = Wstg +                                                  \
          ((size_t)(((((cc) * 4 + (kt_ >> 2)) * 4 + (kt_ & 3)) * 2 + (sb_ >> 1)) * 4 \
                    + (rh * 2 + (sb_ & 1))) << 9) + ((tid & 63) << 3);              \
      char* dp_ = Abuf + (bs) * 8192 + ((q_ * 4 + sb_) << 10) + ((tid & 63) << 4);  \
      __builtin_amdgcn_global_load_lds((const uint32_t*)sp_, (uint32_t*)dp_, 16, 0, 0); \
    }                                                                               \
  } while (0)

// ---- K1: qkv conv (fp16-split MFMA) + BN + LIF -> masks ----
// grid (n, rh): 256 thr / 4 waves; wave = (ks, cp): 64 rows x 64 cols x K/2
__attribute__((amdgpu_waves_per_eu(3, 3)))
__global__ __launch_bounds__(256) void k1q(
    const _Float16* __restrict__ X16, const _Float16* __restrict__ Wstg,
    const float* __restrict__ qg, const float* __restrict__ qb,
    const float* __restrict__ qm, const float* __restrict__ qvar,
    const float* __restrict__ kg, const float* __restrict__ kb,
    const float* __restrict__ km, const float* __restrict__ kvar,
    const float* __restrict__ vg, const float* __restrict__ vb,
    const float* __restrict__ vm, const float* __restrict__ vvar,
    uint32_t* __restrict__ masks) {
  __shared__ __align__(16) char LDSb[16384 + 25600 + 1536 + 4800];
  char* Abuf = LDSb;                           // 2 x 8192
  char* MsB = LDSb + 16384;                    // 25600 (100 cols x 64 rows)
  float* bicL = (float*)(LDSb + 41984);        // 384 f32
  uint32_t* mkL = (uint32_t*)(LDSb + 43520);   // 1200 u32

  const int n = blockIdx.x >> 1, rh = blockIdx.x & 1;
  const int tid = threadIdx.x;
  const int lane = tid & 63, wid = tid >> 6;
  const int ks = wid & 1, cp = wid >> 1;
  const int lr = lane & 31, lkg = lane >> 5;

  // BN-bias table for this block's 64 rows of each of the 6 chunks
  for (int i = tid; i < 384; i += 256) {
    int cc = i >> 6, rl = i & 63;
    int br = cc >> 1, ch = (cc & 1) * 128 + rh * 64 + rl;
    const float* g  = br == 0 ? qg : br == 1 ? kg : vg;
    const float* be = br == 0 ? qb : br == 1 ? kb : vb;
    const float* mu = br == 0 ? qm : br == 1 ? km : vm;
    const float* va = br == 0 ? qvar : br == 1 ? kvar : vvar;
    float sc = g[ch] / sqrtf(va[ch] + 1e-5f);
    bicL[i] = be[ch] - mu[ch] * sc;
  }

  // B: bank the hi panel (2 uses/kt); lo remat'd per phase (1 use/kt)
  const _Float16* xhi = X16 + (size_t)(n * 2) * 25600;
  const _Float16* xlo = xhi + 25600;
  int col0 = cp * 64 + lr;       if (col0 > 99) col0 = 99;
  int col1 = cp * 64 + 32 + lr;  if (col1 > 99) col1 = 99;
  half8_t Bh[16];
#pragma unroll
  for (int ph = 0; ph < 8; ++ph) {
    int kt = ph * 2 + ks;
    Bh[ph]     = *(const half8_t*)(xhi + (kt * 100 + col0) * 16 + lkg * 8);
    Bh[8 + ph] = *(const half8_t*)(xhi + (kt * 100 + col1) * 16 + lkg * 8);
  }
  STAGE_HALF(0, 0, 0);

  for (int c = 0; c < 6; ++c) {
    const int br = c >> 1;
    f32x16 acc00 = {}, acc01 = {}, acc10 = {}, acc11 = {};
#pragma unroll
    for (int ph = 0; ph < 8; ++ph) {
      __syncthreads();                       // phase ph staged & prev reads done
      if (ph < 7) STAGE_HALF(c, (ph + 1) * 2, (ph + 1) & 1);
      else if (c < 5) STAGE_HALF(c + 1, 0, 0);
      const char* base = Abuf + (ph & 1) * 8192 + (ks << 12) + lane * 16;
      half8_t Ah0 = *(const half8_t*)(base);
      half8_t Ah1 = *(const half8_t*)(base + 1024);
      half8_t Al0 = *(const half8_t*)(base + 2048);
      half8_t Al1 = *(const half8_t*)(base + 3072);
      int kt = ph * 2 + ks;
      half8_t Bl0 = *(const half8_t*)(xlo + (kt * 100 + col0) * 16 + lkg * 8);
      half8_t Bl1 = *(const half8_t*)(xlo + (kt * 100 + col1) * 16 + lkg * 8);
      __builtin_amdgcn_s_setprio(1);
      acc00 = mfma16(Ah0, Bh[ph], acc00);
      acc01 = mfma16(Ah0, Bh[8 + ph], acc01);
      acc10 = mfma16(Ah1, Bh[ph], acc10);
      acc11 = mfma16(Ah1, Bh[8 + ph], acc11);
      acc00 = mfma16(Ah0, Bl0, acc00);
      acc01 = mfma16(Ah0, Bl1, acc01);
      acc10 = mfma16(Ah1, Bl0, acc10);
      acc11 = mfma16(Ah1, Bl1, acc11);
      acc00 = mfma16(Al0, Bh[ph], acc00);
      acc01 = mfma16(Al0, Bh[8 + ph], acc01);
      acc10 = mfma16(Al1, Bh[ph], acc10);
      acc11 = mfma16(Al1, Bh[8 + ph], acc11);
      __builtin_amdgcn_s_setprio(0);
    }

    // epilogue: ks0 writes partials, ks1 adds, LIF + ballot -> mkL
    __syncthreads();
    if (ks == 0) {
#pragma unroll
      for (int rtl = 0; rtl < 2; ++rtl) {
#pragma unroll
        for (int ct = 0; ct < 2; ++ct) {
          int col = cp * 64 + ct * 32 + lr;
          if (col < 100) {
            f32x16 A = rtl ? (ct ? acc11 : acc10) : (ct ? acc01 : acc00);
#pragma unroll
            for (int qq = 0; qq < 4; ++qq) {
              int rowb = rtl * 32 + qq * 8 + lkg * 4;
              *(float4*)(MsB + MS_BYTE(col, rowb)) =
                  make_float4(A[qq * 4], A[qq * 4 + 1], A[qq * 4 + 2], A[qq * 4 + 3]);
            }
          }
        }
      }
    }
    __syncthreads();
    if (ks == 1) {
#pragma unroll
      for (int rtl = 0; rtl < 2; ++rtl) {
#pragma unroll
        for (int ct = 0; ct < 2; ++ct) {
          int col = cp * 64 + ct * 32 + lr;
          if (col < 100) {
            f32x16 A = rtl ? (ct ? acc11 : acc10) : (ct ? acc01 : acc00);
#pragma unroll
            for (int qq = 0; qq < 4; ++qq) {
              int rowb = rtl * 32 + qq * 8 + lkg * 4;
              float4* mp = (float4*)(MsB + MS_BYTE(col, rowb));
              float4 old = *mp;
              *mp = make_float4(old.x + A[qq * 4], old.y + A[qq * 4 + 1],
                                old.z + A[qq * 4 + 2], old.w + A[qq * 4 + 3]);
            }
          }
        }
      }
    }
    __syncthreads();
    // LIF over t + ballot pack; tasks = (hgl 0..1, v 0..24)
    const int d = lane & 31, hl = lane >> 5;
    for (int it = 0; it < 7; ++it) {
      int task = it * 8 + wid * 2 + hl;
      bool valid = task < 50;
      int hgl = valid ? task / 25 : 0;
      int v = valid ? task - hgl * 25 : 0;
      int row = hgl * 32 + d;
      float bicv = bicL[c * 64 + row];
      float st = 0.0f;
#pragma unroll
      for (int t = 0; t < 4; ++t) {
        int colx = t * 25 + v;
        float cu = *(const float*)(MsB + MS_BYTE(colx, row)) + bicv;
        st += (cu - st) * 0.5f;
        bool sb = valid && (st >= 1.0f);
        if (st >= 1.0f) st = 0.0f;
        unsigned long long b = __ballot(sb);
        if (valid && (lane == 0 || lane == 32)) {
          uint32_t wd = (lane == 0) ? (uint32_t)b : (uint32_t)(b >> 32);
          mkL[t * 300 + br * 100 + (c & 1) * 50 + hgl * 25 + v] = wd;
        }
      }
    }
  }

  // bulk mask store: global h = (c&1)*4 + rh*2 + hgl
  __syncthreads();
  for (int i = tid; i < 1200; i += 256) {
    int t = i / 300, r = i - t * 300;
    int br = r / 100, r2 = r - br * 100;
    int ch2 = r2 / 50, r3 = r2 - ch2 * 50;
    int hgl = r3 / 25, v = r3 - hgl * 25;
    masks[(size_t)(t * N_ + n) * 600 + br * 200 + ch2 * 100 + (rh * 2 + hgl) * 25 + v] =
        mkL[i];
  }
}

// ---- K2: binary attention (popcount, register-blocked) + attn_lif -> mask2 ----
__launch_bounds__(64)
__global__ void k2_attn(const uint32_t* __restrict__ masks, uint32_t* __restrict__ mask2) {
  __shared__ uint32_t qs[T_][V_], ks_[T_][V_], vs[T_][V_];
  const int n = blockIdx.x >> 3;
  const int h = blockIdx.x & 7;
  const int l = threadIdx.x;
  for (int i = l; i < T_ * 3 * V_; i += 64) {
    int t = i / (3 * V_);
    int r = i - t * (3 * V_);
    int br = r / V_;
    int v = r - br * V_;
    uint32_t w = masks[(size_t)(t * N_ + n) * 600 + br * 200 + h * V_ + v];
    if (br == 0) qs[t][v] = w;
    else if (br == 1) ks_[t][v] = w;
    else vs[t][v] = w;
  }
  __syncthreads();
  const int hi = l >> 5, d = l & 31;
  float st[13];
#pragma unroll
  for (int vv = 0; vv < 13; ++vv) st[vv] = 0.0f;
#pragma unroll
  for (int t = 0; t < 4; ++t) {
    uint32_t q[13];
    int y[13];
#pragma unroll
    for (int vv = 0; vv < 13; ++vv) {
      int v = vv * 2 + hi;
      q[vv] = qs[t][v < V_ ? v : 0];
      y[vv] = 0;
    }
    for (int w = 0; w < V_; ++w) {
      uint32_t kw = ks_[t][w];
      int vb = (int)((vs[t][w] >> d) & 1u);
#pragma unroll
      for (int vv = 0; vv < 13; ++vv) y[vv] += __popc(q[vv] & kw) * vb;
    }
#pragma unroll
    for (int vv = 0; vv < 13; ++vv) {
      int v = vv * 2 + hi;
      bool valid = (v < V_);
      float yf = 0.125f * (float)y[vv];
      st[vv] += (yf - st[vv]) * 0.5f;
      bool s = valid && (st[vv] >= 0.5f);
      if (st[vv] >= 0.5f) st[vv] = 0.0f;
      unsigned long long b = __ballot(s);
      if (valid && (l == 0 || l == 32)) {
        uint32_t wd = (l == 0) ? (uint32_t)b : (uint32_t)(b >> 32);
        mask2[(((size_t)t * N_ + n) * V_ + v) * H_ + h] = wd;
      }
    }
  }
}

// ---- K3: proj conv (binary B, fp16-split W) + bias/BN + LIF + residual ----
// grid (n, q): 256 thr / 4 waves; wave = ct (32 cols) x 64 rows x full K
__attribute__((amdgpu_waves_per_eu(3, 3)))
__global__ __launch_bounds__(256) void k3q(
    const float* __restrict__ x, const _Float16* __restrict__ Wstg,
    const uint32_t* __restrict__ mask2, const float* __restrict__ bp,
    const float* __restrict__ pg, const float* __restrict__ pb,
    const float* __restrict__ pm, const float* __restrict__ pvar,
    float* __restrict__ out) {
  __shared__ __align__(16) char LDSb[16384 + 25600 + 256 + 3200];
  char* Abuf = LDSb;
  char* MsB = LDSb + 16384;
  float* bicL = (float*)(LDSb + 41984);
  uint32_t* m2s = (uint32_t*)(LDSb + 42240);

  const int n = blockIdx.x >> 2, qv = blockIdx.x & 3;
  const int c3 = qv >> 1, rh = qv & 1;
  const int tid = threadIdx.x;
  const int lane = tid & 63, wid = tid >> 6;
  const int lr = lane & 31, lkg = lane >> 5;

  for (int i = tid; i < 800; i += 256) {
    int t = i / 200, r = i - t * 200;
    m2s[i] = mask2[(size_t)(t * N_ + n) * 200 + r];
  }
  if (tid < 64) {
    int ch = qv * 64 + tid;
    float sc = pg[ch] / sqrtf(pvar[ch] + 1e-5f);
    bicL[tid] = fmaf(bp[ch] - pm[ch], sc, pb[ch]);
  }
  __syncthreads();

  // binary B bank: wave's 32 cols, full K (64 VGPR)
  int col = wid * 32 + lr;
  bool cvalid = col < 100;
  int cc = cvalid ? col : 0;
  int tq = cc / 25, vq = cc - tq * 25;
  half8_t Bb[16];
#pragma unroll
  for (int kt = 0; kt < 16; ++kt) {
#pragma unroll
    for (int jj = 0; jj < 8; ++jj) {
      int k = kt * 16 + lkg * 8 + jj;
      uint32_t bit = (m2s[tq * 200 + vq * 8 + (k >> 5)] >> (k & 31)) & 1u;
      Bb[kt][jj] = (cvalid && bit) ? (_Float16)1.0f : (_Float16)0.0f;
    }
  }
  STAGE_HALF(6 + c3, 0, 0);

  f32x16 acc0 = {}, acc1 = {};
#pragma unroll
  for (int ph = 0; ph < 8; ++ph) {
    __syncthreads();
    if (ph < 7) STAGE_HALF(6 + c3, (ph + 1) * 2, (ph + 1) & 1);
#pragma unroll
    for (int q2 = 0; q2 < 2; ++q2) {
      const char* base = Abuf + (ph & 1) * 8192 + (q2 << 12) + lane * 16;
      half8_t Ah0 = *(const half8_t*)(base);
      half8_t Ah1 = *(const half8_t*)(base + 1024);
      half8_t Al0 = *(const half8_t*)(base + 2048);
      half8_t Al1 = *(const half8_t*)(base + 3072);
      const int kt = ph * 2 + q2;
      __builtin_amdgcn_s_setprio(1);
      acc0 = mfma16(Ah0, Bb[kt], acc0);
      acc1 = mfma16(Ah1, Bb[kt], acc1);
      acc0 = mfma16(Al0, Bb[kt], acc0);
      acc1 = mfma16(Al1, Bb[kt], acc1);
      __builtin_amdgcn_s_setprio(0);
    }
  }

  __syncthreads();
  if (cvalid) {
#pragma unroll
    for (int rtl = 0; rtl < 2; ++rtl) {
      f32x16 A = rtl ? acc1 : acc0;
#pragma unroll
      for (int qq = 0; qq < 4; ++qq) {
        int rowb = rtl * 32 + qq * 8 + lkg * 4;
        *(float4*)(MsB + MS_BYTE(col, rowb)) =
            make_float4(A[qq * 4], A[qq * 4 + 1], A[qq * 4 + 2], A[qq * 4 + 3]);
      }
    }
  }
  __syncthreads();
  // LIF (v_th=1.0): write spike back into Ms
  {
    const int d = lane & 31, hl = lane >> 5;
    for (int it = 0; it < 7; ++it) {
      int task = it * 8 + wid * 2 + hl;
      bool valid = task < 50;
      int hgl = valid ? task / 25 : 0;
      int v = valid ? task - hgl * 25 : 0;
      int row = hgl * 32 + d;
      float bicv = bicL[row];
      float st = 0.0f;
#pragma unroll
      for (int t = 0; t < 4; ++t) {
        int colx = t * 25 + v;
        char* mp = MsB + MS_BYTE(colx, row);
        if (valid) {
          float cu = *(const float*)(mp) + bicv;
          st += (cu - st) * 0.5f;
          float sv = (st >= 1.0f) ? 1.0f : 0.0f;
          if (st >= 1.0f) st = 0.0f;
          *(float*)(mp) = sv;
        }
      }
    }
  }
  __syncthreads();
  // residual + store this block's 64 rows
  for (int ii = tid; ii < 6400; ii += 256) {
    int t = ii / 1600, r2 = ii - t * 1600;
    int cl = r2 / 25, v = r2 - cl * 25;
    int colx = t * 25 + v;
    float sv = *(const float*)(MsB + MS_BYTE(colx, cl));
    size_t go = (size_t)(t * N_ + n) * 6400 + (size_t)(qv * 64 + cl) * 25 + v;
    out[go] = sv + x[go];
  }
}

extern "C" void kernel_launch(void* const* d_in, const int* in_sizes, int n_in,
                              void* d_out, int out_size, void* d_ws, size_t ws_size,
                              hipStream_t stream) {
  const float* x    = (const float*)d_in[0];
  const float* wq   = (const float*)d_in[1];
  const float* wk   = (const float*)d_in[2];
  const float* wv   = (const float*)d_in[3];
  const float* wp   = (const float*)d_in[4];
  const float* bp   = (const float*)d_in[5];
  const float* qg   = (const float*)d_in[6];
  const float* qb   = (const float*)d_in[7];
  const float* qm   = (const float*)d_in[8];
  const float* qvar = (const float*)d_in[9];
  const float* kg   = (const float*)d_in[10];
  const float* kb   = (const float*)d_in[11];
  const float* km   = (const float*)d_in[12];
  const float* kvar = (const float*)d_in[13];
  const float* vg   = (const float*)d_in[14];
  const float* vb   = (const float*)d_in[15];
  const float* vm   = (const float*)d_in[16];
  const float* vvar = (const float*)d_in[17];
  const float* pg   = (const float*)d_in[18];
  const float* pb   = (const float*)d_in[19];
  const float* pm   = (const float*)d_in[20];
  const float* pvar = (const float*)d_in[21];

  _Float16* Wstg = (_Float16*)d_ws;                      // 1 MB
  _Float16* X16  = (_Float16*)d_ws + 524288;             // 52.4 MB panels
  uint32_t* masks = (uint32_t*)((char*)d_ws + 1048576 + 52428800);
  uint32_t* mask2 = masks + 1228800;

  kw_stage<<<1024, 512, 0, stream>>>(wq, wk, wv, wp, qg, qvar, kg, kvar,
                                     vg, vvar, pg, pvar, Wstg);
  kx_stage<<<512, 256, 0, stream>>>(x, X16);
  k1q<<<1024, 256, 0, stream>>>(X16, Wstg, qg, qb, qm, qvar, kg, kb, km, kvar,
                                vg, vb, vm, vvar, masks);
  k2_attn<<<4096, 64, 0, stream>>>(masks, mask2);
  k3q<<<2048, 256, 0, stream>>>(x, Wstg, mask2, bp, pg, pb, pm, pvar, (float*)d_out);
}

// Round 10
// 319.748 us; speedup vs baseline: 1.7011x; 1.7011x over previous
//
#include <hip/hip_runtime.h>
#include <cstdint>
#include <cstddef>

#define T_ 4
#define N_ 512
#define C_ 256
#define V_ 25
#define H_ 8

typedef _Float16 half8_t __attribute__((ext_vector_type(8)));
typedef float f32x16 __attribute__((ext_vector_type(16)));

__device__ __forceinline__ f32x16 mfma16(half8_t a, half8_t b, f32x16 c) {
  return __builtin_amdgcn_mfma_f32_32x32x16_f16(a, b, c, 0, 0, 0);
}

// ---- KW: pre-swizzled, BN-scaled, fp16-split weights (verbatim) ----
// Wstg: i = ((((c*4+p)*4+s)*2+m)*4+rt)*512 + lane*8 + j
//   chunks 0..5 = qkv (br=c>>1, rows (c&1)*128+..), 6..7 = proj
__global__ void kw_stage(const float* __restrict__ wq, const float* __restrict__ wk,
                         const float* __restrict__ wv, const float* __restrict__ wp,
                         const float* __restrict__ qg, const float* __restrict__ qvar,
                         const float* __restrict__ kg, const float* __restrict__ kvar,
                         const float* __restrict__ vg, const float* __restrict__ vvar,
                         const float* __restrict__ pg, const float* __restrict__ pvar,
                         _Float16* __restrict__ Wstg) {
  int i = blockIdx.x * 512 + threadIdx.x;          // < 524288
  int j = i & 7, lane = (i >> 3) & 63, rt = (i >> 9) & 3, m = (i >> 11) & 1;
  int s = (i >> 12) & 3, p = (i >> 14) & 3, c = i >> 16;
  int kt = p * 4 + s;
  int row = rt * 32 + (lane & 31);
  int k = kt * 16 + (lane >> 5) * 8 + j;
  const float *w, *g, *va;
  int grow;
  if (c < 6) {
    int br = c >> 1;
    w = br == 0 ? wq : br == 1 ? wk : wv;
    g = br == 0 ? qg : br == 1 ? kg : vg;
    va = br == 0 ? qvar : br == 1 ? kvar : vvar;
    grow = (c & 1) * 128 + row;
  } else {
    w = wp; g = pg; va = pvar;
    grow = (c - 6) * 128 + row;
  }
  float sc = g[grow] / sqrtf(va[grow] + 1e-5f);
  float wv_ = w[grow * 256 + k] * sc;
  _Float16 hi = (_Float16)wv_;
  Wstg[i] = (m == 0) ? hi : (_Float16)(wv_ - (float)hi);
}

// ---- KX: fp16 hi/lo x-panels (r4-verbatim): X16[(2n+m)*100 + col]*256 + k, col = v*4+t ----
__global__ void kx_stage(const float* __restrict__ x, _Float16* __restrict__ X16) {
  __shared__ float Xt[256 * 28];
  const int n = blockIdx.x, tid = threadIdx.x;   // 256 threads
  for (int t = 0; t < 4; ++t) {
    __syncthreads();
    for (int i = tid; i < 6400; i += 256) {
      int k = i / 25, v = i - k * 25;
      Xt[k * 28 + v] = x[(size_t)(t * N_ + n) * 6400 + i];
    }
    __syncthreads();
    for (int j = tid; j < 800; j += 256) {
      int v = j >> 5, kb = j & 31, k0 = kb * 8;
      half8_t hi, lo;
#pragma unroll
      for (int e = 0; e < 8; ++e) {
        float f = Xt[(k0 + e) * 28 + v];
        _Float16 h = (_Float16)f;
        hi[e] = h;
        lo[e] = (_Float16)(f - (float)h);
      }
      size_t base = ((size_t)(2 * n) * 100 + (v * 4 + t)) * 256 + k0;
      *(half8_t*)(X16 + base) = hi;
      *(half8_t*)(X16 + base + 25600) = lo;
    }
  }
}

// Stage one 32KB phase block (4 kt) of Wstg into LDS, lane-linear (verbatim).
#define STAGE_A(gidx, bufsel)                                                     \
  do {                                                                            \
    const _Float16* sp_ = Wstg + (size_t)(gidx) * 16384 + tid * 8;                \
    char* dp_ = Abuf + (bufsel) * 32768 + tid * 16;                               \
    __builtin_amdgcn_global_load_lds((const uint32_t*)(sp_),          (uint32_t*)(dp_),          16, 0, 0); \
    __builtin_amdgcn_global_load_lds((const uint32_t*)(sp_ + 4096),   (uint32_t*)(dp_ + 8192),   16, 0, 0); \
    __builtin_amdgcn_global_load_lds((const uint32_t*)(sp_ + 8192),   (uint32_t*)(dp_ + 16384),  16, 0, 0); \
    __builtin_amdgcn_global_load_lds((const uint32_t*)(sp_ + 12288),  (uint32_t*)(dp_ + 24576),  16, 0, 0); \
  } while (0)

// Ms swizzled byte offset (verbatim — bit-exact r4-r9); rows < 64
#define MS_BYTE(colx, rowx) ((colx) * 256 + (((rowx) * 4) ^ (((colx) & 7) << 4)))

// ---- K1: qkv conv, 2 n per block. 8 waves = rg(2 row-64-halves) x cg(4 col-64-groups) ----
__global__ __launch_bounds__(512, 1) void k1d(
    const _Float16* __restrict__ X16, const _Float16* __restrict__ Wstg,
    const float* __restrict__ qg, const float* __restrict__ qb,
    const float* __restrict__ qm, const float* __restrict__ qvar,
    const float* __restrict__ kg, const float* __restrict__ kb,
    const float* __restrict__ km, const float* __restrict__ kvar,
    const float* __restrict__ vg, const float* __restrict__ vb,
    const float* __restrict__ vm, const float* __restrict__ vvar,
    uint32_t* __restrict__ masks) {
  __shared__ __align__(16) char LDSb[65536 + 51200 + 3072];
  char* Abuf = LDSb;                           // 2 x 32768
  char* MsB = LDSb + 65536;                    // 200 cols x 64 rows f32
  float* bicL = (float*)(LDSb + 65536 + 51200);

  const int np = blockIdx.x, tid = threadIdx.x;
  const int lane = tid & 63, wid = tid >> 6;
  const int rg = wid & 1, cg = wid >> 1;
  const int lr = lane & 31, lkg = lane >> 5;

  for (int i = tid; i < 768; i += 512) {
    int cc = i >> 7, row = i & 127;
    int br = cc >> 1, ch = (cc & 1) * 128 + row;
    const float* g  = br == 0 ? qg : br == 1 ? kg : vg;
    const float* be = br == 0 ? qb : br == 1 ? kb : vb;
    const float* mu = br == 0 ? qm : br == 1 ? km : vm;
    const float* va = br == 0 ? qvar : br == 1 ? kvar : vvar;
    float sc = g[ch] / sqrtf(va[ch] + 1e-5f);
    bicL[i] = be[ch] - mu[ch] * sc;
  }

  // per-lane B column pointers (clamped for pad cols; chunk-invariant)
  const int colw0 = cg * 64 + lr, colw1 = cg * 64 + 32 + lr;
  int c0 = colw0 > 199 ? 199 : colw0, c1 = colw1 > 199 ? 199 : colw1;
  int nl0 = (c0 >= 100), cl0 = c0 - nl0 * 100;
  int nl1 = (c1 >= 100), cl1 = c1 - nl1 * 100;
  const _Float16* xh0 = X16 + ((size_t)((np * 2 + nl0) * 2 + 0)) * 25600 + cl0 * 256 + lkg * 8;
  const _Float16* xl0 = X16 + ((size_t)((np * 2 + nl0) * 2 + 1)) * 25600 + cl0 * 256 + lkg * 8;
  const _Float16* xh1 = X16 + ((size_t)((np * 2 + nl1) * 2 + 0)) * 25600 + cl1 * 256 + lkg * 8;
  const _Float16* xl1 = X16 + ((size_t)((np * 2 + nl1) * 2 + 1)) * 25600 + cl1 * 256 + lkg * 8;

  STAGE_A(0, 0);
  half8_t Bh0[2], Bh1[2], Bl0[2], Bl1[2];
  Bh0[0] = *(const half8_t*)(xh0);
  Bh1[0] = *(const half8_t*)(xh1);
  Bl0[0] = *(const half8_t*)(xl0);
  Bl1[0] = *(const half8_t*)(xl1);

  for (int c = 0; c < 6; ++c) {
    const int br = c >> 1;
    f32x16 acc00 = {}, acc01 = {}, acc10 = {}, acc11 = {};
#pragma unroll
    for (int p = 0; p < 4; ++p) {
      __syncthreads();                        // phase-p A staged; prev reads done
      int gnext = c * 4 + p + 1;
      if (gnext < 24) STAGE_A(gnext, (p + 1) & 1);
#pragma unroll
      for (int s = 0; s < 4; ++s) {
        const int kt = p * 4 + s;
        const int cur = kt & 1, nxt = cur ^ 1;
        const int ktn = ((kt + 1) & 15) * 16;
        Bh0[nxt] = *(const half8_t*)(xh0 + ktn);   // prefetch kt+1 (B chunk-invariant)
        Bh1[nxt] = *(const half8_t*)(xh1 + ktn);
        Bl0[nxt] = *(const half8_t*)(xl0 + ktn);
        Bl1[nxt] = *(const half8_t*)(xl1 + ktn);
        const char* base = Abuf + (p & 1) * 32768 + s * 8192 + (rg * 2) * 1024 + lane * 16;
        half8_t Ah0 = *(const half8_t*)(base);
        half8_t Ah1 = *(const half8_t*)(base + 1024);
        half8_t Al0 = *(const half8_t*)(base + 4096);
        half8_t Al1 = *(const half8_t*)(base + 4096 + 1024);
        __builtin_amdgcn_s_setprio(1);
        acc00 = mfma16(Ah0, Bh0[cur], acc00);
        acc01 = mfma16(Ah0, Bh1[cur], acc01);
        acc10 = mfma16(Ah1, Bh0[cur], acc10);
        acc11 = mfma16(Ah1, Bh1[cur], acc11);
        acc00 = mfma16(Ah0, Bl0[cur], acc00);
        acc01 = mfma16(Ah0, Bl1[cur], acc01);
        acc10 = mfma16(Ah1, Bl0[cur], acc10);
        acc11 = mfma16(Ah1, Bl1[cur], acc11);
        acc00 = mfma16(Al0, Bh0[cur], acc00);
        acc01 = mfma16(Al0, Bh1[cur], acc01);
        acc10 = mfma16(Al1, Bh0[cur], acc10);
        acc11 = mfma16(Al1, Bh1[cur], acc11);
        __builtin_amdgcn_s_setprio(0);
      }
    }

    // epilogue: two row-halves; rg==pp waves own that half's rows
#pragma unroll
    for (int pp = 0; pp < 2; ++pp) {
      __syncthreads();
      if (rg == pp) {
#pragma unroll
        for (int sub = 0; sub < 2; ++sub) {
#pragma unroll
          for (int ct = 0; ct < 2; ++ct) {
            int col = ct ? colw1 : colw0;
            if (col < 200) {
              f32x16 A = sub ? (ct ? acc11 : acc10) : (ct ? acc01 : acc00);
#pragma unroll
              for (int qq = 0; qq < 4; ++qq) {
                int rowb = sub * 32 + qq * 8 + lkg * 4;
                *(float4*)(MsB + MS_BYTE(col, rowb)) =
                    make_float4(A[qq * 4], A[qq * 4 + 1], A[qq * 4 + 2], A[qq * 4 + 3]);
              }
            }
          }
        }
      }
      __syncthreads();
      // LIF + ballot pack: 100 tasks = nl(2) x hgl(2) x v(25)
      const int d = lane & 31, hl = lane >> 5;
      for (int it = 0; it < 7; ++it) {
        int task = it * 16 + wid * 2 + hl;
        bool valid = task < 100;
        int tnl = valid ? task / 50 : 0;
        int r = valid ? task - tnl * 50 : 0;
        int hgl = r / 25, v = r - (r / 25) * 25;
        int row = hgl * 32 + d;
        float bicv = bicL[c * 128 + pp * 64 + row];
        float st = 0.0f;
#pragma unroll
        for (int t = 0; t < 4; ++t) {
          int colx = tnl * 100 + v * 4 + t;
          float cu = *(const float*)(MsB + MS_BYTE(colx, row)) + bicv;
          st += (cu - st) * 0.5f;
          bool sb = valid && (st >= 1.0f);
          if (st >= 1.0f) st = 0.0f;
          unsigned long long b = __ballot(sb);
          if (valid && (lane == 0 || lane == 32)) {
            uint32_t wd = (lane == 0) ? (uint32_t)b : (uint32_t)(b >> 32);
            int hg = (c & 1) * 4 + pp * 2 + hgl;
            int n = np * 2 + tnl;
            masks[((((size_t)t * N_ + n) * 3 + br) * H_ + hg) * V_ + v] = wd;
          }
        }
      }
    }
  }
}

// ---- K2: binary attention (popcount, register-blocked) + attn_lif -> mask2 ----
__launch_bounds__(64)
__global__ void k2_attn(const uint32_t* __restrict__ masks, uint32_t* __restrict__ mask2) {
  __shared__ uint32_t qs[T_][V_], ks_[T_][V_], vs[T_][V_];
  const int n = blockIdx.x >> 3;
  const int h = blockIdx.x & 7;
  const int l = threadIdx.x;
  for (int i = l; i < T_ * 3 * V_; i += 64) {
    int t = i / (3 * V_);
    int r = i - t * (3 * V_);
    int br = r / V_;
    int v = r - br * V_;
    uint32_t w = masks[(((size_t)t * N_ + n) * 3 + br) * (H_ * V_) + h * V_ + v];
    if (br == 0) qs[t][v] = w;
    else if (br == 1) ks_[t][v] = w;
    else vs[t][v] = w;
  }
  __syncthreads();
  const int hi = l >> 5, d = l & 31;
  float st[13];
#pragma unroll
  for (int vv = 0; vv < 13; ++vv) st[vv] = 0.0f;
#pragma unroll
  for (int t = 0; t < 4; ++t) {
    uint32_t q[13];
    int y[13];
#pragma unroll
    for (int vv = 0; vv < 13; ++vv) {
      int v = vv * 2 + hi;
      q[vv] = qs[t][v < V_ ? v : 0];
      y[vv] = 0;
    }
    for (int w = 0; w < V_; ++w) {
      uint32_t kw = ks_[t][w];
      int vb = (int)((vs[t][w] >> d) & 1u);
#pragma unroll
      for (int vv = 0; vv < 13; ++vv) y[vv] += __popc(q[vv] & kw) * vb;
    }
#pragma unroll
    for (int vv = 0; vv < 13; ++vv) {
      int v = vv * 2 + hi;
      bool valid = (v < V_);
      float yf = 0.125f * (float)y[vv];
      st[vv] += (yf - st[vv]) * 0.5f;
      bool s = valid && (st[vv] >= 0.5f);
      if (st[vv] >= 0.5f) st[vv] = 0.0f;
      unsigned long long b = __ballot(s);
      if (valid && (l == 0 || l == 32)) {
        uint32_t wd = (l == 0) ? (uint32_t)b : (uint32_t)(b >> 32);
        mask2[(((size_t)t * N_ + n) * V_ + v) * H_ + h] = wd;
      }
    }
  }
}

// ---- K3: proj conv, 2 n per block; binary B from LDS mask bits ----
__global__ __launch_bounds__(512, 1) void k3d(
    const float* __restrict__ x, const _Float16* __restrict__ Wstg,
    const uint32_t* __restrict__ mask2, const float* __restrict__ bp,
    const float* __restrict__ pg, const float* __restrict__ pb,
    const float* __restrict__ pm, const float* __restrict__ pvar,
    float* __restrict__ out) {
  __shared__ __align__(16) char LDSb[65536 + 51200 + 1024 + 6400];
  char* Abuf = LDSb;
  char* MsB = LDSb + 65536;
  float* bicL = (float*)(LDSb + 65536 + 51200);
  uint32_t* m2s = (uint32_t*)(LDSb + 65536 + 51200 + 1024);   // [nl][800]

  const int np = blockIdx.x, tid = threadIdx.x;
  const int lane = tid & 63, wid = tid >> 6;
  const int rg = wid & 1, cg = wid >> 1;
  const int lr = lane & 31, lkg = lane >> 5;

  for (int i = tid; i < 1600; i += 512) {
    int nl = i / 800, j = i - nl * 800;
    int t = j / 200, r = j - t * 200;
    m2s[i] = mask2[(size_t)(t * N_ + np * 2 + nl) * 200 + r];
  }
  if (tid < 256) {
    float sc = pg[tid] / sqrtf(pvar[tid] + 1e-5f);
    bicL[tid] = fmaf(bp[tid] - pm[tid], sc, pb[tid]);
  }
  __syncthreads();

  const int colw0 = cg * 64 + lr, colw1 = cg * 64 + 32 + lr;
  int c0 = colw0 > 199 ? 199 : colw0, c1 = colw1 > 199 ? 199 : colw1;
  int nl0 = (c0 >= 100), cl0 = c0 - nl0 * 100;
  int nl1 = (c1 >= 100), cl1 = c1 - nl1 * 100;
  const int v0 = cl0 >> 2, t0 = cl0 & 3, v1 = cl1 >> 2, t1 = cl1 & 3;
  const int mb0 = nl0 * 800 + t0 * 200 + v0 * 8;
  const int mb1 = nl1 * 800 + t1 * 200 + v1 * 8;

  STAGE_A(24, 0);
  for (int c = 0; c < 2; ++c) {
    f32x16 acc00 = {}, acc01 = {}, acc10 = {}, acc11 = {};
#pragma unroll
    for (int p = 0; p < 4; ++p) {
      __syncthreads();
      int gnext = 24 + c * 4 + p + 1;
      if (gnext < 32) STAGE_A(gnext, (p + 1) & 1);
#pragma unroll
      for (int s = 0; s < 4; ++s) {
        const int kt = p * 4 + s;
        uint32_t w0 = m2s[mb0 + (kt >> 1)];
        uint32_t w1 = m2s[mb1 + (kt >> 1)];
        int sh = (kt & 1) * 16 + lkg * 8;
        half8_t B0, B1;
#pragma unroll
        for (int jj = 0; jj < 8; ++jj) {
          B0[jj] = ((w0 >> (sh + jj)) & 1u) ? (_Float16)1.0f : (_Float16)0.0f;
          B1[jj] = ((w1 >> (sh + jj)) & 1u) ? (_Float16)1.0f : (_Float16)0.0f;
        }
        const char* base = Abuf + (p & 1) * 32768 + s * 8192 + (rg * 2) * 1024 + lane * 16;
        half8_t Ah0 = *(const half8_t*)(base);
        half8_t Ah1 = *(const half8_t*)(base + 1024);
        half8_t Al0 = *(const half8_t*)(base + 4096);
        half8_t Al1 = *(const half8_t*)(base + 4096 + 1024);
        __builtin_amdgcn_s_setprio(1);
        acc00 = mfma16(Ah0, B0, acc00);
        acc01 = mfma16(Ah0, B1, acc01);
        acc10 = mfma16(Ah1, B0, acc10);
        acc11 = mfma16(Ah1, B1, acc11);
        acc00 = mfma16(Al0, B0, acc00);
        acc01 = mfma16(Al0, B1, acc01);
        acc10 = mfma16(Al1, B0, acc10);
        acc11 = mfma16(Al1, B1, acc11);
        __builtin_amdgcn_s_setprio(0);
      }
    }

#pragma unroll
    for (int pp = 0; pp < 2; ++pp) {
      __syncthreads();
      if (rg == pp) {
#pragma unroll
        for (int sub = 0; sub < 2; ++sub) {
#pragma unroll
          for (int ct = 0; ct < 2; ++ct) {
            int col = ct ? colw1 : colw0;
            if (col < 200) {
              f32x16 A = sub ? (ct ? acc11 : acc10) : (ct ? acc01 : acc00);
#pragma unroll
              for (int qq = 0; qq < 4; ++qq) {
                int rowb = sub * 32 + qq * 8 + lkg * 4;
                *(float4*)(MsB + MS_BYTE(col, rowb)) =
                    make_float4(A[qq * 4], A[qq * 4 + 1], A[qq * 4 + 2], A[qq * 4 + 3]);
              }
            }
          }
        }
      }
      __syncthreads();
      // LIF: write spikes back into Ms
      {
        const int d = lane & 31, hl = lane >> 5;
        for (int it = 0; it < 7; ++it) {
          int task = it * 16 + wid * 2 + hl;
          bool valid = task < 100;
          int tnl = valid ? task / 50 : 0;
          int r = valid ? task - tnl * 50 : 0;
          int hgl = r / 25, v = r - (r / 25) * 25;
          int row = hgl * 32 + d;
          float bicv = bicL[c * 128 + pp * 64 + row];
          float st = 0.0f;
#pragma unroll
          for (int t = 0; t < 4; ++t) {
            int colx = tnl * 100 + v * 4 + t;
            char* mp = MsB + MS_BYTE(colx, row);
            if (valid) {
              float cu = *(const float*)(mp) + bicv;
              st += (cu - st) * 0.5f;
              float sv = (st >= 1.0f) ? 1.0f : 0.0f;
              if (st >= 1.0f) st = 0.0f;
              *(float*)(mp) = sv;
            }
          }
        }
      }
      __syncthreads();
      // residual + store this (c,pp) row-half for both n
      for (int ii = tid; ii < 12800; ii += 512) {
        int t = ii / 3200, r = ii - t * 3200;
        int nl = r / 1600, r2 = r - nl * 1600;
        int cl = r2 / 25, v = r2 - cl * 25;
        int colx = nl * 100 + v * 4 + t;
        float sv = *(const float*)(MsB + MS_BYTE(colx, cl));
        size_t go = (size_t)(t * N_ + np * 2 + nl) * 6400 +
                    (size_t)(c * 128 + pp * 64 + cl) * 25 + v;
        out[go] = sv + x[go];
      }
    }
  }
}

extern "C" void kernel_launch(void* const* d_in, const int* in_sizes, int n_in,
                              void* d_out, int out_size, void* d_ws, size_t ws_size,
                              hipStream_t stream) {
  const float* x    = (const float*)d_in[0];
  const float* wq   = (const float*)d_in[1];
  const float* wk   = (const float*)d_in[2];
  const float* wv   = (const float*)d_in[3];
  const float* wp   = (const float*)d_in[4];
  const float* bp   = (const float*)d_in[5];
  const float* qg   = (const float*)d_in[6];
  const float* qb   = (const float*)d_in[7];
  const float* qm   = (const float*)d_in[8];
  const float* qvar = (const float*)d_in[9];
  const float* kg   = (const float*)d_in[10];
  const float* kb   = (const float*)d_in[11];
  const float* km   = (const float*)d_in[12];
  const float* kvar = (const float*)d_in[13];
  const float* vg   = (const float*)d_in[14];
  const float* vb   = (const float*)d_in[15];
  const float* vm   = (const float*)d_in[16];
  const float* vvar = (const float*)d_in[17];
  const float* pg   = (const float*)d_in[18];
  const float* pb   = (const float*)d_in[19];
  const float* pm   = (const float*)d_in[20];
  const float* pvar = (const float*)d_in[21];

  _Float16* Wstg = (_Float16*)d_ws;                      // 1 MB
  _Float16* X16  = (_Float16*)d_ws + 524288;             // 52.4 MB panels
  uint32_t* masks = (uint32_t*)((char*)d_ws + 1048576 + 52428800);
  uint32_t* mask2 = masks + 1228800;

  kw_stage<<<1024, 512, 0, stream>>>(wq, wk, wv, wp, qg, qvar, kg, kvar,
                                     vg, vvar, pg, pvar, Wstg);
  kx_stage<<<512, 256, 0, stream>>>(x, X16);
  k1d<<<256, 512, 0, stream>>>(X16, Wstg, qg, qb, qm, qvar, kg, kb, km, kvar,
                               vg, vb, vm, vvar, masks);
  k2_attn<<<4096, 64, 0, stream>>>(masks, mask2);
  k3d<<<256, 512, 0, stream>>>(x, Wstg, mask2, bp, pg, pb, pm, pvar, (float*)d_out);
}

// Round 11
// 316.839 us; speedup vs baseline: 1.7167x; 1.0092x over previous
//
#include <hip/hip_runtime.h>
#include <cstdint>
#include <cstddef>

#define T_ 4
#define N_ 512
#define C_ 256
#define V_ 25
#define H_ 8

typedef _Float16 half8_t __attribute__((ext_vector_type(8)));
typedef float f32x16 __attribute__((ext_vector_type(16)));

__device__ __forceinline__ f32x16 mfma16(half8_t a, half8_t b, f32x16 c) {
  return __builtin_amdgcn_mfma_f32_32x32x16_f16(a, b, c, 0, 0, 0);
}

// ---- KW: pre-swizzled, BN-scaled, fp16-split weights (verbatim) ----
// Wstg: i = ((((c*4+p)*4+s)*2+m)*4+rt)*512 + lane*8 + j
//   chunks 0..5 = qkv (br=c>>1, rows (c&1)*128+..), 6..7 = proj
__global__ void kw_stage(const float* __restrict__ wq, const float* __restrict__ wk,
                         const float* __restrict__ wv, const float* __restrict__ wp,
                         const float* __restrict__ qg, const float* __restrict__ qvar,
                         const float* __restrict__ kg, const float* __restrict__ kvar,
                         const float* __restrict__ vg, const float* __restrict__ vvar,
                         const float* __restrict__ pg, const float* __restrict__ pvar,
                         _Float16* __restrict__ Wstg) {
  int i = blockIdx.x * 512 + threadIdx.x;          // < 524288
  int j = i & 7, lane = (i >> 3) & 63, rt = (i >> 9) & 3, m = (i >> 11) & 1;
  int s = (i >> 12) & 3, p = (i >> 14) & 3, c = i >> 16;
  int kt = p * 4 + s;
  int row = rt * 32 + (lane & 31);
  int k = kt * 16 + (lane >> 5) * 8 + j;
  const float *w, *g, *va;
  int grow;
  if (c < 6) {
    int br = c >> 1;
    w = br == 0 ? wq : br == 1 ? wk : wv;
    g = br == 0 ? qg : br == 1 ? kg : vg;
    va = br == 0 ? qvar : br == 1 ? kvar : vvar;
    grow = (c & 1) * 128 + row;
  } else {
    w = wp; g = pg; va = pvar;
    grow = (c - 6) * 128 + row;
  }
  float sc = g[grow] / sqrtf(va[grow] + 1e-5f);
  float wv_ = w[grow * 256 + k] * sc;
  _Float16 hi = (_Float16)wv_;
  Wstg[i] = (m == 0) ? hi : (_Float16)(wv_ - (float)hi);
}

// ---- KX: fp16 hi/lo x-panels, kt-major coalesced-read layout ----
// X16 idx(n,m,kt,col,e) = (n*2+m)*25600 + kt*1600 + col*16 + e ; col = v*4+t ; k = kt*16+e
__global__ void kx_stage(const float* __restrict__ x, _Float16* __restrict__ X16) {
  __shared__ float Xt[256 * 28];
  const int n = blockIdx.x, tid = threadIdx.x;   // 256 threads
  for (int t = 0; t < 4; ++t) {
    __syncthreads();
    for (int i = tid; i < 6400; i += 256) {
      int k = i / 25, v = i - k * 25;
      Xt[k * 28 + v] = x[(size_t)(t * N_ + n) * 6400 + i];
    }
    __syncthreads();
    // 800 tasks: (kt 16) x (v 25) x (lkg 2)
    for (int jj = tid; jj < 800; jj += 256) {
      int kt = jj / 50, r = jj - kt * 50;
      int v = r >> 1, lkg = r & 1;
      int k0 = kt * 16 + lkg * 8;
      half8_t hi, lo;
#pragma unroll
      for (int e = 0; e < 8; ++e) {
        float f = Xt[(k0 + e) * 28 + v];
        _Float16 h = (_Float16)f;
        hi[e] = h;
        lo[e] = (_Float16)(f - (float)h);
      }
      int col = v * 4 + t;
      size_t base = (size_t)(n * 2) * 25600 + kt * 1600 + col * 16 + lkg * 8;
      *(half8_t*)(X16 + base) = hi;
      *(half8_t*)(X16 + base + 25600) = lo;
    }
  }
}

// Stage one 32KB phase block (4 kt) of Wstg into LDS, lane-linear (verbatim).
#define STAGE_A(gidx, bufsel)                                                     \
  do {                                                                            \
    const _Float16* sp_ = Wstg + (size_t)(gidx) * 16384 + tid * 8;                \
    char* dp_ = Abuf + (bufsel) * 32768 + tid * 16;                               \
    __builtin_amdgcn_global_load_lds((const uint32_t*)(sp_),          (uint32_t*)(dp_),          16, 0, 0); \
    __builtin_amdgcn_global_load_lds((const uint32_t*)(sp_ + 4096),   (uint32_t*)(dp_ + 8192),   16, 0, 0); \
    __builtin_amdgcn_global_load_lds((const uint32_t*)(sp_ + 8192),   (uint32_t*)(dp_ + 16384),  16, 0, 0); \
    __builtin_amdgcn_global_load_lds((const uint32_t*)(sp_ + 12288),  (uint32_t*)(dp_ + 24576),  16, 0, 0); \
  } while (0)

// Ms swizzled byte offset (verbatim — bit-exact r4-r10); rows < 64
#define MS_BYTE(colx, rowx) ((colx) * 256 + (((rowx) * 4) ^ (((colx) & 7) << 4)))

// ---- K1: qkv conv, 2 n per block. 8 waves = rg(2 row-64-halves) x cg(4 col-64-groups) ----
__global__ __launch_bounds__(512, 1) void k1d(
    const _Float16* __restrict__ X16, const _Float16* __restrict__ Wstg,
    const float* __restrict__ qg, const float* __restrict__ qb,
    const float* __restrict__ qm, const float* __restrict__ qvar,
    const float* __restrict__ kg, const float* __restrict__ kb,
    const float* __restrict__ km, const float* __restrict__ kvar,
    const float* __restrict__ vg, const float* __restrict__ vb,
    const float* __restrict__ vm, const float* __restrict__ vvar,
    uint32_t* __restrict__ masks) {
  __shared__ __align__(16) char LDSb[65536 + 51200 + 3072];
  char* Abuf = LDSb;                           // 2 x 32768
  char* MsB = LDSb + 65536;                    // 200 cols x 64 rows f32
  float* bicL = (float*)(LDSb + 65536 + 51200);

  const int np = blockIdx.x, tid = threadIdx.x;
  const int lane = tid & 63, wid = tid >> 6;
  const int rg = wid & 1, cg = wid >> 1;
  const int lr = lane & 31, lkg = lane >> 5;

  for (int i = tid; i < 768; i += 512) {
    int cc = i >> 7, row = i & 127;
    int br = cc >> 1, ch = (cc & 1) * 128 + row;
    const float* g  = br == 0 ? qg : br == 1 ? kg : vg;
    const float* be = br == 0 ? qb : br == 1 ? kb : vb;
    const float* mu = br == 0 ? qm : br == 1 ? km : vm;
    const float* va = br == 0 ? qvar : br == 1 ? kvar : vvar;
    float sc = g[ch] / sqrtf(va[ch] + 1e-5f);
    bicL[i] = be[ch] - mu[ch] * sc;
  }

  // per-lane B column pointers (clamped for pad cols; chunk-invariant), kt-major layout
  const int colw0 = cg * 64 + lr, colw1 = cg * 64 + 32 + lr;
  int c0 = colw0 > 199 ? 199 : colw0, c1 = colw1 > 199 ? 199 : colw1;
  int nl0 = (c0 >= 100), cl0 = c0 - nl0 * 100;
  int nl1 = (c1 >= 100), cl1 = c1 - nl1 * 100;
  const _Float16* xh0 = X16 + (size_t)((np * 2 + nl0) * 2 + 0) * 25600 + cl0 * 16 + lkg * 8;
  const _Float16* xl0 = X16 + (size_t)((np * 2 + nl0) * 2 + 1) * 25600 + cl0 * 16 + lkg * 8;
  const _Float16* xh1 = X16 + (size_t)((np * 2 + nl1) * 2 + 0) * 25600 + cl1 * 16 + lkg * 8;
  const _Float16* xl1 = X16 + (size_t)((np * 2 + nl1) * 2 + 1) * 25600 + cl1 * 16 + lkg * 8;

  STAGE_A(0, 0);
  half8_t Bh0[2], Bh1[2], Bl0[2], Bl1[2];
  Bh0[0] = *(const half8_t*)(xh0);
  Bh1[0] = *(const half8_t*)(xh1);
  Bl0[0] = *(const half8_t*)(xl0);
  Bl1[0] = *(const half8_t*)(xl1);

  for (int c = 0; c < 6; ++c) {
    const int br = c >> 1;
    f32x16 acc00 = {}, acc01 = {}, acc10 = {}, acc11 = {};
#pragma unroll
    for (int p = 0; p < 4; ++p) {
      __syncthreads();                        // phase-p A staged; prev reads done
      int gnext = c * 4 + p + 1;
      if (gnext < 24) STAGE_A(gnext, (p + 1) & 1);
#pragma unroll
      for (int s = 0; s < 4; ++s) {
        const int kt = p * 4 + s;
        const int cur = kt & 1, nxt = cur ^ 1;
        const int ktn = ((kt + 1) & 15) * 1600;
        Bh0[nxt] = *(const half8_t*)(xh0 + ktn);   // prefetch kt+1 (B chunk-invariant)
        Bh1[nxt] = *(const half8_t*)(xh1 + ktn);
        Bl0[nxt] = *(const half8_t*)(xl0 + ktn);
        Bl1[nxt] = *(const half8_t*)(xl1 + ktn);
        const char* base = Abuf + (p & 1) * 32768 + s * 8192 + (rg * 2) * 1024 + lane * 16;
        half8_t Ah0 = *(const half8_t*)(base);
        half8_t Ah1 = *(const half8_t*)(base + 1024);
        half8_t Al0 = *(const half8_t*)(base + 4096);
        half8_t Al1 = *(const half8_t*)(base + 4096 + 1024);
        __builtin_amdgcn_s_setprio(1);
        acc00 = mfma16(Ah0, Bh0[cur], acc00);
        acc01 = mfma16(Ah0, Bh1[cur], acc01);
        acc10 = mfma16(Ah1, Bh0[cur], acc10);
        acc11 = mfma16(Ah1, Bh1[cur], acc11);
        acc00 = mfma16(Ah0, Bl0[cur], acc00);
        acc01 = mfma16(Ah0, Bl1[cur], acc01);
        acc10 = mfma16(Ah1, Bl0[cur], acc10);
        acc11 = mfma16(Ah1, Bl1[cur], acc11);
        acc00 = mfma16(Al0, Bh0[cur], acc00);
        acc01 = mfma16(Al0, Bh1[cur], acc01);
        acc10 = mfma16(Al1, Bh0[cur], acc10);
        acc11 = mfma16(Al1, Bh1[cur], acc11);
        __builtin_amdgcn_s_setprio(0);
      }
    }

    // epilogue: two row-halves; rg==pp waves own that half's rows
#pragma unroll
    for (int pp = 0; pp < 2; ++pp) {
      __syncthreads();
      if (rg == pp) {
#pragma unroll
        for (int sub = 0; sub < 2; ++sub) {
#pragma unroll
          for (int ct = 0; ct < 2; ++ct) {
            int col = ct ? colw1 : colw0;
            if (col < 200) {
              f32x16 A = sub ? (ct ? acc11 : acc10) : (ct ? acc01 : acc00);
#pragma unroll
              for (int qq = 0; qq < 4; ++qq) {
                int rowb = sub * 32 + qq * 8 + lkg * 4;
                *(float4*)(MsB + MS_BYTE(col, rowb)) =
                    make_float4(A[qq * 4], A[qq * 4 + 1], A[qq * 4 + 2], A[qq * 4 + 3]);
              }
            }
          }
        }
      }
      __syncthreads();
      // LIF + ballot pack: 100 tasks = nl(2) x hgl(2) x v(25)
      const int d = lane & 31, hl = lane >> 5;
      for (int it = 0; it < 7; ++it) {
        int task = it * 16 + wid * 2 + hl;
        bool valid = task < 100;
        int tnl = valid ? task / 50 : 0;
        int r = valid ? task - tnl * 50 : 0;
        int hgl = r / 25, v = r - (r / 25) * 25;
        int row = hgl * 32 + d;
        float bicv = bicL[c * 128 + pp * 64 + row];
        float st = 0.0f;
#pragma unroll
        for (int t = 0; t < 4; ++t) {
          int colx = tnl * 100 + v * 4 + t;
          float cu = *(const float*)(MsB + MS_BYTE(colx, row)) + bicv;
          st += (cu - st) * 0.5f;
          bool sb = valid && (st >= 1.0f);
          if (st >= 1.0f) st = 0.0f;
          unsigned long long b = __ballot(sb);
          if (valid && (lane == 0 || lane == 32)) {
            uint32_t wd = (lane == 0) ? (uint32_t)b : (uint32_t)(b >> 32);
            int hg = (c & 1) * 4 + pp * 2 + hgl;
            int n = np * 2 + tnl;
            masks[((((size_t)t * N_ + n) * 3 + br) * H_ + hg) * V_ + v] = wd;
          }
        }
      }
    }
  }
}

// ---- K2: binary attention (popcount, register-blocked) + attn_lif -> mask2 ----
__launch_bounds__(64)
__global__ void k2_attn(const uint32_t* __restrict__ masks, uint32_t* __restrict__ mask2) {
  __shared__ uint32_t qs[T_][V_], ks_[T_][V_], vs[T_][V_];
  const int n = blockIdx.x >> 3;
  const int h = blockIdx.x & 7;
  const int l = threadIdx.x;
  for (int i = l; i < T_ * 3 * V_; i += 64) {
    int t = i / (3 * V_);
    int r = i - t * (3 * V_);
    int br = r / V_;
    int v = r - br * V_;
    uint32_t w = masks[(((size_t)t * N_ + n) * 3 + br) * (H_ * V_) + h * V_ + v];
    if (br == 0) qs[t][v] = w;
    else if (br == 1) ks_[t][v] = w;
    else vs[t][v] = w;
  }
  __syncthreads();
  const int hi = l >> 5, d = l & 31;
  float st[13];
#pragma unroll
  for (int vv = 0; vv < 13; ++vv) st[vv] = 0.0f;
#pragma unroll
  for (int t = 0; t < 4; ++t) {
    uint32_t q[13];
    int y[13];
#pragma unroll
    for (int vv = 0; vv < 13; ++vv) {
      int v = vv * 2 + hi;
      q[vv] = qs[t][v < V_ ? v : 0];
      y[vv] = 0;
    }
    for (int w = 0; w < V_; ++w) {
      uint32_t kw = ks_[t][w];
      int vb = (int)((vs[t][w] >> d) & 1u);
#pragma unroll
      for (int vv = 0; vv < 13; ++vv) y[vv] += __popc(q[vv] & kw) * vb;
    }
#pragma unroll
    for (int vv = 0; vv < 13; ++vv) {
      int v = vv * 2 + hi;
      bool valid = (v < V_);
      float yf = 0.125f * (float)y[vv];
      st[vv] += (yf - st[vv]) * 0.5f;
      bool s = valid && (st[vv] >= 0.5f);
      if (st[vv] >= 0.5f) st[vv] = 0.0f;
      unsigned long long b = __ballot(s);
      if (valid && (l == 0 || l == 32)) {
        uint32_t wd = (l == 0) ? (uint32_t)b : (uint32_t)(b >> 32);
        mask2[(((size_t)t * N_ + n) * V_ + v) * H_ + h] = wd;
      }
    }
  }
}

// ---- K3: proj conv, 2 n per block; binary B from LDS mask bits (verbatim r10) ----
__global__ __launch_bounds__(512, 1) void k3d(
    const float* __restrict__ x, const _Float16* __restrict__ Wstg,
    const uint32_t* __restrict__ mask2, const float* __restrict__ bp,
    const float* __restrict__ pg, const float* __restrict__ pb,
    const float* __restrict__ pm, const float* __restrict__ pvar,
    float* __restrict__ out) {
  __shared__ __align__(16) char LDSb[65536 + 51200 + 1024 + 6400];
  char* Abuf = LDSb;
  char* MsB = LDSb + 65536;
  float* bicL = (float*)(LDSb + 65536 + 51200);
  uint32_t* m2s = (uint32_t*)(LDSb + 65536 + 51200 + 1024);   // [nl][800]

  const int np = blockIdx.x, tid = threadIdx.x;
  const int lane = tid & 63, wid = tid >> 6;
  const int rg = wid & 1, cg = wid >> 1;
  const int lr = lane & 31, lkg = lane >> 5;

  for (int i = tid; i < 1600; i += 512) {
    int nl = i / 800, j = i - nl * 800;
    int t = j / 200, r = j - t * 200;
    m2s[i] = mask2[(size_t)(t * N_ + np * 2 + nl) * 200 + r];
  }
  if (tid < 256) {
    float sc = pg[tid] / sqrtf(pvar[tid] + 1e-5f);
    bicL[tid] = fmaf(bp[tid] - pm[tid], sc, pb[tid]);
  }
  __syncthreads();

  const int colw0 = cg * 64 + lr, colw1 = cg * 64 + 32 + lr;
  int c0 = colw0 > 199 ? 199 : colw0, c1 = colw1 > 199 ? 199 : colw1;
  int nl0 = (c0 >= 100), cl0 = c0 - nl0 * 100;
  int nl1 = (c1 >= 100), cl1 = c1 - nl1 * 100;
  const int v0 = cl0 >> 2, t0 = cl0 & 3, v1 = cl1 >> 2, t1 = cl1 & 3;
  const int mb0 = nl0 * 800 + t0 * 200 + v0 * 8;
  const int mb1 = nl1 * 800 + t1 * 200 + v1 * 8;

  STAGE_A(24, 0);
  for (int c = 0; c < 2; ++c) {
    f32x16 acc00 = {}, acc01 = {}, acc10 = {}, acc11 = {};
#pragma unroll
    for (int p = 0; p < 4; ++p) {
      __syncthreads();
      int gnext = 24 + c * 4 + p + 1;
      if (gnext < 32) STAGE_A(gnext, (p + 1) & 1);
#pragma unroll
      for (int s = 0; s < 4; ++s) {
        const int kt = p * 4 + s;
        uint32_t w0 = m2s[mb0 + (kt >> 1)];
        uint32_t w1 = m2s[mb1 + (kt >> 1)];
        int sh = (kt & 1) * 16 + lkg * 8;
        half8_t B0, B1;
#pragma unroll
        for (int jj = 0; jj < 8; ++jj) {
          B0[jj] = ((w0 >> (sh + jj)) & 1u) ? (_Float16)1.0f : (_Float16)0.0f;
          B1[jj] = ((w1 >> (sh + jj)) & 1u) ? (_Float16)1.0f : (_Float16)0.0f;
        }
        const char* base = Abuf + (p & 1) * 32768 + s * 8192 + (rg * 2) * 1024 + lane * 16;
        half8_t Ah0 = *(const half8_t*)(base);
        half8_t Ah1 = *(const half8_t*)(base + 1024);
        half8_t Al0 = *(const half8_t*)(base + 4096);
        half8_t Al1 = *(const half8_t*)(base + 4096 + 1024);
        __builtin_amdgcn_s_setprio(1);
        acc00 = mfma16(Ah0, B0, acc00);
        acc01 = mfma16(Ah0, B1, acc01);
        acc10 = mfma16(Ah1, B0, acc10);
        acc11 = mfma16(Ah1, B1, acc11);
        acc00 = mfma16(Al0, B0, acc00);
        acc01 = mfma16(Al0, B1, acc01);
        acc10 = mfma16(Al1, B0, acc10);
        acc11 = mfma16(Al1, B1, acc11);
        __builtin_amdgcn_s_setprio(0);
      }
    }

#pragma unroll
    for (int pp = 0; pp < 2; ++pp) {
      __syncthreads();
      if (rg == pp) {
#pragma unroll
        for (int sub = 0; sub < 2; ++sub) {
#pragma unroll
          for (int ct = 0; ct < 2; ++ct) {
            int col = ct ? colw1 : colw0;
            if (col < 200) {
              f32x16 A = sub ? (ct ? acc11 : acc10) : (ct ? acc01 : acc00);
#pragma unroll
              for (int qq = 0; qq < 4; ++qq) {
                int rowb = sub * 32 + qq * 8 + lkg * 4;
                *(float4*)(MsB + MS_BYTE(col, rowb)) =
                    make_float4(A[qq * 4], A[qq * 4 + 1], A[qq * 4 + 2], A[qq * 4 + 3]);
              }
            }
          }
        }
      }
      __syncthreads();
      // LIF: write spikes back into Ms
      {
        const int d = lane & 31, hl = lane >> 5;
        for (int it = 0; it < 7; ++it) {
          int task = it * 16 + wid * 2 + hl;
          bool valid = task < 100;
          int tnl = valid ? task / 50 : 0;
          int r = valid ? task - tnl * 50 : 0;
          int hgl = r / 25, v = r - (r / 25) * 25;
          int row = hgl * 32 + d;
          float bicv = bicL[c * 128 + pp * 64 + row];
          float st = 0.0f;
#pragma unroll
          for (int t = 0; t < 4; ++t) {
            int colx = tnl * 100 + v * 4 + t;
            char* mp = MsB + MS_BYTE(colx, row);
            if (valid) {
              float cu = *(const float*)(mp) + bicv;
              st += (cu - st) * 0.5f;
              float sv = (st >= 1.0f) ? 1.0f : 0.0f;
              if (st >= 1.0f) st = 0.0f;
              *(float*)(mp) = sv;
            }
          }
        }
      }
      __syncthreads();
      // residual + store this (c,pp) row-half for both n
      for (int ii = tid; ii < 12800; ii += 512) {
        int t = ii / 3200, r = ii - t * 3200;
        int nl = r / 1600, r2 = r - nl * 1600;
        int cl = r2 / 25, v = r2 - cl * 25;
        int colx = nl * 100 + v * 4 + t;
        float sv = *(const float*)(MsB + MS_BYTE(colx, cl));
        size_t go = (size_t)(t * N_ + np * 2 + nl) * 6400 +
                    (size_t)(c * 128 + pp * 64 + cl) * 25 + v;
        out[go] = sv + x[go];
      }
    }
  }
}

extern "C" void kernel_launch(void* const* d_in, const int* in_sizes, int n_in,
                              void* d_out, int out_size, void* d_ws, size_t ws_size,
                              hipStream_t stream) {
  const float* x    = (const float*)d_in[0];
  const float* wq   = (const float*)d_in[1];
  const float* wk   = (const float*)d_in[2];
  const float* wv   = (const float*)d_in[3];
  const float* wp   = (const float*)d_in[4];
  const float* bp   = (const float*)d_in[5];
  const float* qg   = (const float*)d_in[6];
  const float* qb   = (const float*)d_in[7];
  const float* qm   = (const float*)d_in[8];
  const float* qvar = (const float*)d_in[9];
  const float* kg   = (const float*)d_in[10];
  const float* kb   = (const float*)d_in[11];
  const float* km   = (const float*)d_in[12];
  const float* kvar = (const float*)d_in[13];
  const float* vg   = (const float*)d_in[14];
  const float* vb   = (const float*)d_in[15];
  const float* vm   = (const float*)d_in[16];
  const float* vvar = (const float*)d_in[17];
  const float* pg   = (const float*)d_in[18];
  const float* pb   = (const float*)d_in[19];
  const float* pm   = (const float*)d_in[20];
  const float* pvar = (const float*)d_in[21];

  _Float16* Wstg = (_Float16*)d_ws;                      // 1 MB
  _Float16* X16  = (_Float16*)d_ws + 524288;             // 52.4 MB panels
  uint32_t* masks = (uint32_t*)((char*)d_ws + 1048576 + 52428800);
  uint32_t* mask2 = masks + 1228800;

  kw_stage<<<1024, 512, 0, stream>>>(wq, wk, wv, wp, qg, qvar, kg, kvar,
                                     vg, vvar, pg, pvar, Wstg);
  kx_stage<<<512, 256, 0, stream>>>(x, X16);
  k1d<<<256, 512, 0, stream>>>(X16, Wstg, qg, qb, qm, qvar, kg, kb, km, kvar,
                               vg, vb, vm, vvar, masks);
  k2_attn<<<4096, 64, 0, stream>>>(masks, mask2);
  k3d<<<256, 512, 0, stream>>>(x, Wstg, mask2, bp, pg, pb, pm, pvar, (float*)d_out);
}